// Round 7
// baseline (965.194 us; speedup 1.0000x reference)
//
#include <hip/hip_runtime.h>
#include <hip/hip_bf16.h>

#define NN 100000      // nodes
#define NE 1600000     // edges
#define DIM 128        // feature dim
#define NG 512         // graphs
#define NB 391         // scan blocks = ceil(NN/256)
#define GR 32          // gather: rows staged per wave per batch

typedef __attribute__((ext_vector_type(8))) short bf16x8;
typedef __attribute__((ext_vector_type(4))) float f32x4;

__device__ inline short f2bf(float f) {
    union { __hip_bfloat16 h; short s; } u;
    u.h = __float2bfloat16(f);
    return u.s;
}
__device__ inline float bf2f(short s) {
    return __uint_as_float(((unsigned int)(unsigned short)s) << 16);
}

// swizzled element offset of W^T[c][k] in LDS
__device__ inline int wt_off(int c, int k) {
    return c * DIM + ((((k >> 3) ^ (c & 15)) << 3) | (k & 7));
}

// async global->LDS row stage: 64 lanes x 4B, LDS dest = base + lane*4.
typedef const __attribute__((address_space(1))) unsigned int* as1_u32p;
typedef __attribute__((address_space(3))) unsigned int* as3_u32p;
__device__ inline void row_to_lds(const unsigned int* g, unsigned int* l) {
    __builtin_amdgcn_global_load_lds((as1_u32p)(uintptr_t)g,
                                     (as3_u32p)(uintptr_t)l, 4, 0, 0);
}

// ---------------------------------------------------------------------------
// degree histograms: 4 edges/thread (independent atomic chains)
__global__ __launch_bounds__(256) void hist_kernel(const int* __restrict__ src,
                                                   const int* __restrict__ dst,
                                                   int* __restrict__ cin,
                                                   int* __restrict__ cout) {
    int base = (blockIdx.x * 256 + threadIdx.x) * 4;
    if (base >= NE) return;                 // NE % 4 == 0
    int4 s = *(const int4*)&src[base];
    int4 d = *(const int4*)&dst[base];
    atomicAdd(&cout[s.x], 1); atomicAdd(&cout[s.y], 1);
    atomicAdd(&cout[s.z], 1); atomicAdd(&cout[s.w], 1);
    atomicAdd(&cin[d.x], 1);  atomicAdd(&cin[d.y], 1);
    atomicAdd(&cin[d.z], 1);  atomicAdd(&cin[d.w], 1);
}

__global__ __launch_bounds__(256) void norm_kernel(const int* __restrict__ cin,
                                                   const int* __restrict__ cout,
                                                   float* __restrict__ norm_src,
                                                   float* __restrict__ norm_dst) {
    int i = blockIdx.x * 256 + threadIdx.x;
    if (i < NN) {
        norm_src[i] = rsqrtf((float)max(cout[i], 1));
        norm_dst[i] = rsqrtf((float)max(cin[i], 1));
    }
}

// ---------------------------------------------------------------------------
// exclusive scan of cin -> row_start (2-level)
__global__ __launch_bounds__(256) void scan1_kernel(const int* __restrict__ cin,
                                                    int* __restrict__ row,
                                                    int* __restrict__ bsum) {
    __shared__ int t[256];
    int i = blockIdx.x * 256 + threadIdx.x;
    int v = (i < NN) ? cin[i] : 0;
    t[threadIdx.x] = v;
    __syncthreads();
    for (int off = 1; off < 256; off <<= 1) {
        int x = (threadIdx.x >= off) ? t[threadIdx.x - off] : 0;
        __syncthreads();
        t[threadIdx.x] += x;
        __syncthreads();
    }
    if (i < NN) row[i] = t[threadIdx.x] - v;
    if (threadIdx.x == 255) bsum[blockIdx.x] = t[255];
}

__global__ __launch_bounds__(512) void scan2_kernel(int* __restrict__ bsum) {
    __shared__ int t[512];
    int v = (threadIdx.x < NB) ? bsum[threadIdx.x] : 0;
    t[threadIdx.x] = v;
    __syncthreads();
    for (int off = 1; off < 512; off <<= 1) {
        int x = (threadIdx.x >= off) ? t[threadIdx.x - off] : 0;
        __syncthreads();
        t[threadIdx.x] += x;
        __syncthreads();
    }
    if (threadIdx.x < NB) bsum[threadIdx.x] = t[threadIdx.x] - v;
}

// adds block offsets; also initializes cursor = row
__global__ __launch_bounds__(256) void scan3_kernel(int* __restrict__ row,
                                                    const int* __restrict__ bsum,
                                                    int* __restrict__ cursor) {
    int i = blockIdx.x * 256 + threadIdx.x;
    if (i < NN) {
        int r = row[i] + bsum[i >> 8];
        row[i] = r;
        cursor[i] = r;
    }
    if (i == 0) row[NN] = NE;
}

// fill CSR: 4 edges/thread, independent atomic->store chains
__global__ __launch_bounds__(256) void fill_kernel(const int* __restrict__ src,
                                                   const int* __restrict__ dst,
                                                   int* __restrict__ cursor,
                                                   int* __restrict__ esrc) {
    int base = (blockIdx.x * 256 + threadIdx.x) * 4;
    if (base >= NE) return;
    int4 s = *(const int4*)&src[base];
    int4 d = *(const int4*)&dst[base];
    int p0 = atomicAdd(&cursor[d.x], 1);
    int p1 = atomicAdd(&cursor[d.y], 1);
    int p2 = atomicAdd(&cursor[d.z], 1);
    int p3 = atomicAdd(&cursor[d.w], 1);
    esrc[p0] = s.x; esrc[p1] = s.y; esrc[p2] = s.z; esrc[p3] = s.w;
}

// graph start offsets: gstart[g] = lower_bound(gids, g)
__global__ __launch_bounds__(256) void gstart_kernel(const int* __restrict__ gids,
                                                     int* __restrict__ gstart) {
    int g = blockIdx.x * 256 + threadIdx.x;
    if (g > NG) return;
    int lo = 0, hi = NN;
    while (lo < hi) {
        int mid = (lo + hi) >> 1;
        if (gids[mid] < g) lo = mid + 1; else hi = mid;
    }
    gstart[g] = lo;
}

// ---------------------------------------------------------------------------
// Layer-1 MFMA GEMM: X(bf16)[n,:] = (h[n,:] * ns[n]) @ W1   (h fp32)
__global__ __launch_bounds__(256) void gemm1_mfma(
    const float* __restrict__ Xin, const float* __restrict__ norm_src,
    const float* __restrict__ W, __hip_bfloat16* __restrict__ Xout) {
    __shared__ __hip_bfloat16 Wt[DIM * DIM];
    for (int idx = threadIdx.x; idx < DIM * DIM; idx += 256) {
        int k = idx >> 7, c = idx & 127;
        Wt[wt_off(c, k)] = __float2bfloat16(W[idx]);
    }
    __syncthreads();

    const int wave = threadIdx.x >> 6;
    const int lane = threadIdx.x & 63;
    const int tile = blockIdx.x * 4 + wave;
    if (tile >= NN / 16) return;
    const int row0 = tile * 16;
    const int lr = lane & 15;
    const int q  = lane >> 4;
    const int row = row0 + lr;

    const float ns = norm_src[row];
    bf16x8 afrag[4];
#pragma unroll
    for (int kt = 0; kt < 4; kt++) {
        const int k0 = kt * 32 + q * 8;
        const float* p = Xin + row * DIM + k0;
#pragma unroll
        for (int j = 0; j < 8; j++) ((short*)&afrag[kt])[j] = f2bf(p[j] * ns);
    }
#pragma unroll
    for (int nt = 0; nt < 8; nt++) {
        f32x4 acc = {0.f, 0.f, 0.f, 0.f};
        const int c = nt * 16 + lr;
#pragma unroll
        for (int kt = 0; kt < 4; kt++) {
            bf16x8 b = *(const bf16x8*)&Wt[wt_off(c, kt * 32 + q * 8)];
            acc = __builtin_amdgcn_mfma_f32_16x16x32_bf16(afrag[kt], b, acc, 0, 0, 0);
        }
#pragma unroll
        for (int r = 0; r < 4; r++)
            Xout[(row0 + q * 4 + r) * DIM + c] = __float2bfloat16(acc[r]);
    }
}

// Layer-2 MFMA GEMM: X(bf16)[n,:] = (relu(agg*nd+b1)*ns) @ W2  (agg bf16)
__global__ __launch_bounds__(256) void gemm2_mfma(
    const __hip_bfloat16* __restrict__ Xin, const float* __restrict__ norm_src,
    const float* __restrict__ norm_dst, const float* __restrict__ bias,
    const float* __restrict__ W, __hip_bfloat16* __restrict__ Xout) {
    __shared__ __hip_bfloat16 Wt[DIM * DIM];
    for (int idx = threadIdx.x; idx < DIM * DIM; idx += 256) {
        int k = idx >> 7, c = idx & 127;
        Wt[wt_off(c, k)] = __float2bfloat16(W[idx]);
    }
    __syncthreads();

    const int wave = threadIdx.x >> 6;
    const int lane = threadIdx.x & 63;
    const int tile = blockIdx.x * 4 + wave;
    if (tile >= NN / 16) return;
    const int row0 = tile * 16;
    const int lr = lane & 15;
    const int q  = lane >> 4;
    const int row = row0 + lr;

    const float ns = norm_src[row];
    const float nd = norm_dst[row];
    bf16x8 afrag[4];
#pragma unroll
    for (int kt = 0; kt < 4; kt++) {
        const int k0 = kt * 32 + q * 8;
        bf16x8 raw = *(const bf16x8*)&Xin[row * DIM + k0];
#pragma unroll
        for (int j = 0; j < 8; j++) {
            float v = fmaxf(bf2f(raw[j]) * nd + bias[k0 + j], 0.0f) * ns;
            ((short*)&afrag[kt])[j] = f2bf(v);
        }
    }
#pragma unroll
    for (int nt = 0; nt < 8; nt++) {
        f32x4 acc = {0.f, 0.f, 0.f, 0.f};
        const int c = nt * 16 + lr;
#pragma unroll
        for (int kt = 0; kt < 4; kt++) {
            bf16x8 b = *(const bf16x8*)&Wt[wt_off(c, kt * 32 + q * 8)];
            acc = __builtin_amdgcn_mfma_f32_16x16x32_bf16(afrag[kt], b, acc, 0, 0, 0);
        }
#pragma unroll
        for (int r = 0; r < 4; r++)
            Xout[(row0 + q * 4 + r) * DIM + c] = __float2bfloat16(acc[r]);
    }
}

// ---------------------------------------------------------------------------
// CSR gather, one wave per node, async global->LDS staging.
// ROUND-6 LESSON: vmcnt is FIFO — interleaving esrc loads (vmcnt) with
// dependent global_load_lds (vmcnt) forces a full drain per edge (~2200
// cyc/edge, matching the measured 285us across rounds 4/5/6). Fix: fetch all
// batch indices with ONE vector load (lanes 0..31), broadcast via readlane
// (register-only), then issue all glds back-to-back; single vmcnt(0) drain.
// FUSE=0: write aggregated row as packed bf16 pairs.
// FUSE=1: fused readout — v = sum_j relu(agg_j*nd+b2_j)*W3_j, one atomic/node.
template <int FUSE>
__global__ __launch_bounds__(256) void gather_kernel(
    const int* __restrict__ row, const int* __restrict__ esrc,
    const unsigned int* __restrict__ Xb, unsigned int* __restrict__ AGGb,
    const float* __restrict__ norm_dst, const float* __restrict__ b2,
    const float* __restrict__ W3, const int* __restrict__ gids,
    float* __restrict__ gsum) {
    __shared__ unsigned int buf[4][GR][64];    // 32 KB: per-wave staging
    const int wave = threadIdx.x >> 6;
    const int lane = threadIdx.x & 63;
    const int n = (blockIdx.x * 256 + threadIdx.x) >> 6;   // wave-uniform
    const int s0 = row[n], s1 = row[n + 1];
    float ax0 = 0.f, ay0 = 0.f, ax1 = 0.f, ay1 = 0.f;

    for (int e = s0; e < s1; ) {
        const int cnt = min(GR, s1 - e);       // wave-uniform
        // one vector load fetches the whole batch's indices into lanes 0..cnt-1
        int li = (lane < cnt) ? esrc[e + lane] : 0;
        // broadcast each index to SGPR and issue glds back-to-back (no waits)
#pragma unroll
        for (int r = 0; r < GR; r++) {
            if (r < cnt) {
                int idx = __builtin_amdgcn_readlane(li, r);
                row_to_lds(Xb + idx * 64 + lane, &buf[wave][r][0]);
            }
        }
        __builtin_amdgcn_s_waitcnt(0x0F70);                // vmcnt(0)
        __builtin_amdgcn_wave_barrier();
#pragma unroll
        for (int r = 0; r < GR; r += 2) {
            if (r < cnt) {
                unsigned int u = buf[wave][r][lane];
                ax0 += __uint_as_float(u << 16);
                ay0 += __uint_as_float(u & 0xffff0000u);
            }
            if (r + 1 < cnt) {
                unsigned int u = buf[wave][r + 1][lane];
                ax1 += __uint_as_float(u << 16);
                ay1 += __uint_as_float(u & 0xffff0000u);
            }
        }
        __builtin_amdgcn_wave_barrier();   // keep next batch's LDS writes below reads
        e += cnt;
    }
    float ax = ax0 + ax1, ay = ay0 + ay1;

    if (FUSE == 0) {
        unsigned int lo = (unsigned int)(unsigned short)f2bf(ax);
        unsigned int hi = (unsigned int)(unsigned short)f2bf(ay);
        AGGb[n * 64 + lane] = lo | (hi << 16);
    } else {
        int j = lane * 2;
        float nd = norm_dst[n];
        float v = fmaxf(ax * nd + b2[j], 0.0f) * W3[j]
                + fmaxf(ay * nd + b2[j + 1], 0.0f) * W3[j + 1];
#pragma unroll
        for (int off = 32; off; off >>= 1) v += __shfl_down(v, off);
        if (lane == 0) atomicAdd(&gsum[gids[n]], v);
    }
}

// out[g] = gsum[g] / max(cnt,1) + b3
__global__ __launch_bounds__(256) void final_kernel(
    const float* __restrict__ gsum, const int* __restrict__ gstart,
    const float* __restrict__ b3, float* __restrict__ out) {
    int g = blockIdx.x * 256 + threadIdx.x;
    if (g < NG) {
        float cnt = (float)(gstart[g + 1] - gstart[g]);
        out[g] = gsum[g] / fmaxf(cnt, 1.0f) + b3[0];
    }
}

// ---------------------------------------------------------------------------
extern "C" void kernel_launch(void* const* d_in, const int* in_sizes, int n_in,
                              void* d_out, int out_size, void* d_ws, size_t ws_size,
                              hipStream_t stream) {
    const float* h   = (const float*)d_in[0];
    const int* src   = (const int*)d_in[1];
    const int* dst   = (const int*)d_in[2];
    const int* gids  = (const int*)d_in[3];
    const float* W1  = (const float*)d_in[5];
    const float* b1  = (const float*)d_in[6];
    const float* W2  = (const float*)d_in[7];
    const float* b2  = (const float*)d_in[8];
    const float* W3  = (const float*)d_in[9];
    const float* b3  = (const float*)d_in[10];

    // workspace layout (256B-aligned)
    const size_t OFF_NRM  = 0;                 // 2*NN fp32
    const size_t OFF_CIN  = 800256;            // NN int
    const size_t OFF_COUT = 1200640;           // NN int
    const size_t OFF_ROW  = 1601024;           // NN+1 int
    const size_t OFF_CUR  = 2001664;           // NN int
    const size_t OFF_BSUM = 2402304;           // NB int
    const size_t OFF_GST  = 2404352;           // NG+1 int
    const size_t OFF_GSUM = 2406656;           // NG fp32
    const size_t OFF_ESRC = 2408704;           // NE int
    const size_t OFF_X    = 8808960;           // NN*DIM bf16
    const size_t OFF_AGG  = 34408960;          // NN*DIM bf16
    const size_t REQUIRED = 60008960;          // ~60 MB
    if (ws_size < REQUIRED) {
        hipMemsetAsync(d_out, 0, out_size * sizeof(float), stream);
        return;
    }
    char* ws = (char*)d_ws;
    float* norm_src = (float*)(ws + OFF_NRM);
    float* norm_dst = norm_src + NN;
    int*   cin      = (int*)(ws + OFF_CIN);
    int*   cout_    = (int*)(ws + OFF_COUT);
    int*   row      = (int*)(ws + OFF_ROW);
    int*   cursor   = (int*)(ws + OFF_CUR);
    int*   bsum     = (int*)(ws + OFF_BSUM);
    int*   gstart   = (int*)(ws + OFF_GST);
    float* gsum     = (float*)(ws + OFF_GSUM);
    int*   esrc     = (int*)(ws + OFF_ESRC);
    __hip_bfloat16* X    = (__hip_bfloat16*)(ws + OFF_X);
    unsigned int*   Xb   = (unsigned int*)(ws + OFF_X);
    __hip_bfloat16* AGG  = (__hip_bfloat16*)(ws + OFF_AGG);
    unsigned int*   AGGb = (unsigned int*)(ws + OFF_AGG);

    const int eb = (NE / 4 + 255) / 256;

    // 1. CSR build + norms (+ gsum zero)
    hipMemsetAsync(cin, 0, 800768, stream);    // cin + cout contiguous
    hipMemsetAsync(gsum, 0, 2048, stream);
    hist_kernel<<<eb, 256, 0, stream>>>(src, dst, cin, cout_);
    norm_kernel<<<(NN + 255) / 256, 256, 0, stream>>>(cin, cout_, norm_src, norm_dst);
    scan1_kernel<<<NB, 256, 0, stream>>>(cin, row, bsum);
    scan2_kernel<<<1, 512, 0, stream>>>(bsum);
    scan3_kernel<<<NB, 256, 0, stream>>>(row, bsum, cursor);
    fill_kernel<<<eb, 256, 0, stream>>>(src, dst, cursor, esrc);
    gstart_kernel<<<3, 256, 0, stream>>>(gids, gstart);

    const int gemm_grid = (NN / 16 + 3) / 4;

    // 2. layer 1: project (MFMA, bf16 out), CSR gather (bf16 out)
    gemm1_mfma<<<gemm_grid, 256, 0, stream>>>(h, norm_src, W1, X);
    gather_kernel<0><<<NN / 4, 256, 0, stream>>>(row, esrc, Xb, AGGb,
                                                 norm_dst, b2, W3, gids, gsum);

    // 3. layer 2: fused pre-op + project, then gather fused with readout
    gemm2_mfma<<<gemm_grid, 256, 0, stream>>>(AGG, norm_src, norm_dst, b1, W2, X);
    gather_kernel<1><<<NN / 4, 256, 0, stream>>>(row, esrc, Xb, AGGb,
                                                 norm_dst, b2, W3, gids, gsum);

    // 4. final: per-graph mean + bias
    final_kernel<<<2, 256, 0, stream>>>(gsum, gstart, b3, (float*)d_out);
}

// Round 8
// 725.312 us; speedup vs baseline: 1.3307x; 1.3307x over previous
//
#include <hip/hip_runtime.h>
#include <hip/hip_bf16.h>

#define NN 100000      // nodes
#define NE 1600000     // edges
#define DIM 128        // feature dim
#define NG 512         // graphs
#define NB 391         // scan blocks = ceil(NN/256)
#define GR 16          // gather: rows staged per wave per batch

typedef __attribute__((ext_vector_type(8))) short bf16x8;
typedef __attribute__((ext_vector_type(4))) float f32x4;

__device__ inline short f2bf(float f) {
    union { __hip_bfloat16 h; short s; } u;
    u.h = __float2bfloat16(f);
    return u.s;
}
__device__ inline float bf2f(short s) {
    return __uint_as_float(((unsigned int)(unsigned short)s) << 16);
}

// swizzled element offset of W^T[c][k] in LDS
__device__ inline int wt_off(int c, int k) {
    return c * DIM + ((((k >> 3) ^ (c & 15)) << 3) | (k & 7));
}

// async global->LDS stage, width=16: 64 lanes x 16B, LDS dest = base + lane*16.
// One instruction stages FOUR 256B feature rows (lane>>4 = row, lane&15 = 16B chunk).
typedef const __attribute__((address_space(1))) unsigned int* as1_u32p;
typedef __attribute__((address_space(3))) unsigned int* as3_u32p;
__device__ inline void rows4_to_lds(const unsigned int* g, unsigned int* l) {
    __builtin_amdgcn_global_load_lds((as1_u32p)(uintptr_t)g,
                                     (as3_u32p)(uintptr_t)l, 16, 0, 0);
}

// ---------------------------------------------------------------------------
// degree histograms: 4 edges/thread (independent atomic chains)
__global__ __launch_bounds__(256) void hist_kernel(const int* __restrict__ src,
                                                   const int* __restrict__ dst,
                                                   int* __restrict__ cin,
                                                   int* __restrict__ cout) {
    int base = (blockIdx.x * 256 + threadIdx.x) * 4;
    if (base >= NE) return;                 // NE % 4 == 0
    int4 s = *(const int4*)&src[base];
    int4 d = *(const int4*)&dst[base];
    atomicAdd(&cout[s.x], 1); atomicAdd(&cout[s.y], 1);
    atomicAdd(&cout[s.z], 1); atomicAdd(&cout[s.w], 1);
    atomicAdd(&cin[d.x], 1);  atomicAdd(&cin[d.y], 1);
    atomicAdd(&cin[d.z], 1);  atomicAdd(&cin[d.w], 1);
}

__global__ __launch_bounds__(256) void norm_kernel(const int* __restrict__ cin,
                                                   const int* __restrict__ cout,
                                                   float* __restrict__ norm_src,
                                                   float* __restrict__ norm_dst) {
    int i = blockIdx.x * 256 + threadIdx.x;
    if (i < NN) {
        norm_src[i] = rsqrtf((float)max(cout[i], 1));
        norm_dst[i] = rsqrtf((float)max(cin[i], 1));
    }
}

// ---------------------------------------------------------------------------
// exclusive scan of cin -> row_start (2-level)
__global__ __launch_bounds__(256) void scan1_kernel(const int* __restrict__ cin,
                                                    int* __restrict__ row,
                                                    int* __restrict__ bsum) {
    __shared__ int t[256];
    int i = blockIdx.x * 256 + threadIdx.x;
    int v = (i < NN) ? cin[i] : 0;
    t[threadIdx.x] = v;
    __syncthreads();
    for (int off = 1; off < 256; off <<= 1) {
        int x = (threadIdx.x >= off) ? t[threadIdx.x - off] : 0;
        __syncthreads();
        t[threadIdx.x] += x;
        __syncthreads();
    }
    if (i < NN) row[i] = t[threadIdx.x] - v;
    if (threadIdx.x == 255) bsum[blockIdx.x] = t[255];
}

__global__ __launch_bounds__(512) void scan2_kernel(int* __restrict__ bsum) {
    __shared__ int t[512];
    int v = (threadIdx.x < NB) ? bsum[threadIdx.x] : 0;
    t[threadIdx.x] = v;
    __syncthreads();
    for (int off = 1; off < 512; off <<= 1) {
        int x = (threadIdx.x >= off) ? t[threadIdx.x - off] : 0;
        __syncthreads();
        t[threadIdx.x] += x;
        __syncthreads();
    }
    if (threadIdx.x < NB) bsum[threadIdx.x] = t[threadIdx.x] - v;
}

// adds block offsets; also initializes cursor = row
__global__ __launch_bounds__(256) void scan3_kernel(int* __restrict__ row,
                                                    const int* __restrict__ bsum,
                                                    int* __restrict__ cursor) {
    int i = blockIdx.x * 256 + threadIdx.x;
    if (i < NN) {
        int r = row[i] + bsum[i >> 8];
        row[i] = r;
        cursor[i] = r;
    }
    if (i == 0) row[NN] = NE;
}

// fill CSR: 4 edges/thread, independent atomic->store chains
__global__ __launch_bounds__(256) void fill_kernel(const int* __restrict__ src,
                                                   const int* __restrict__ dst,
                                                   int* __restrict__ cursor,
                                                   int* __restrict__ esrc) {
    int base = (blockIdx.x * 256 + threadIdx.x) * 4;
    if (base >= NE) return;
    int4 s = *(const int4*)&src[base];
    int4 d = *(const int4*)&dst[base];
    int p0 = atomicAdd(&cursor[d.x], 1);
    int p1 = atomicAdd(&cursor[d.y], 1);
    int p2 = atomicAdd(&cursor[d.z], 1);
    int p3 = atomicAdd(&cursor[d.w], 1);
    esrc[p0] = s.x; esrc[p1] = s.y; esrc[p2] = s.z; esrc[p3] = s.w;
}

// graph start offsets: gstart[g] = lower_bound(gids, g)
__global__ __launch_bounds__(256) void gstart_kernel(const int* __restrict__ gids,
                                                     int* __restrict__ gstart) {
    int g = blockIdx.x * 256 + threadIdx.x;
    if (g > NG) return;
    int lo = 0, hi = NN;
    while (lo < hi) {
        int mid = (lo + hi) >> 1;
        if (gids[mid] < g) lo = mid + 1; else hi = mid;
    }
    gstart[g] = lo;
}

// ---------------------------------------------------------------------------
// Layer-1 MFMA GEMM: X(bf16)[n,:] = (h[n,:] * ns[n]) @ W1   (h fp32)
__global__ __launch_bounds__(256) void gemm1_mfma(
    const float* __restrict__ Xin, const float* __restrict__ norm_src,
    const float* __restrict__ W, __hip_bfloat16* __restrict__ Xout) {
    __shared__ __hip_bfloat16 Wt[DIM * DIM];
    for (int idx = threadIdx.x; idx < DIM * DIM; idx += 256) {
        int k = idx >> 7, c = idx & 127;
        Wt[wt_off(c, k)] = __float2bfloat16(W[idx]);
    }
    __syncthreads();

    const int wave = threadIdx.x >> 6;
    const int lane = threadIdx.x & 63;
    const int tile = blockIdx.x * 4 + wave;
    if (tile >= NN / 16) return;
    const int row0 = tile * 16;
    const int lr = lane & 15;
    const int q  = lane >> 4;
    const int row = row0 + lr;

    const float ns = norm_src[row];
    bf16x8 afrag[4];
#pragma unroll
    for (int kt = 0; kt < 4; kt++) {
        const int k0 = kt * 32 + q * 8;
        const float* p = Xin + row * DIM + k0;
#pragma unroll
        for (int j = 0; j < 8; j++) ((short*)&afrag[kt])[j] = f2bf(p[j] * ns);
    }
#pragma unroll
    for (int nt = 0; nt < 8; nt++) {
        f32x4 acc = {0.f, 0.f, 0.f, 0.f};
        const int c = nt * 16 + lr;
#pragma unroll
        for (int kt = 0; kt < 4; kt++) {
            bf16x8 b = *(const bf16x8*)&Wt[wt_off(c, kt * 32 + q * 8)];
            acc = __builtin_amdgcn_mfma_f32_16x16x32_bf16(afrag[kt], b, acc, 0, 0, 0);
        }
#pragma unroll
        for (int r = 0; r < 4; r++)
            Xout[(row0 + q * 4 + r) * DIM + c] = __float2bfloat16(acc[r]);
    }
}

// Layer-2 MFMA GEMM: X(bf16)[n,:] = (relu(agg*nd+b1)*ns) @ W2  (agg bf16)
__global__ __launch_bounds__(256) void gemm2_mfma(
    const __hip_bfloat16* __restrict__ Xin, const float* __restrict__ norm_src,
    const float* __restrict__ norm_dst, const float* __restrict__ bias,
    const float* __restrict__ W, __hip_bfloat16* __restrict__ Xout) {
    __shared__ __hip_bfloat16 Wt[DIM * DIM];
    for (int idx = threadIdx.x; idx < DIM * DIM; idx += 256) {
        int k = idx >> 7, c = idx & 127;
        Wt[wt_off(c, k)] = __float2bfloat16(W[idx]);
    }
    __syncthreads();

    const int wave = threadIdx.x >> 6;
    const int lane = threadIdx.x & 63;
    const int tile = blockIdx.x * 4 + wave;
    if (tile >= NN / 16) return;
    const int row0 = tile * 16;
    const int lr = lane & 15;
    const int q  = lane >> 4;
    const int row = row0 + lr;

    const float ns = norm_src[row];
    const float nd = norm_dst[row];
    bf16x8 afrag[4];
#pragma unroll
    for (int kt = 0; kt < 4; kt++) {
        const int k0 = kt * 32 + q * 8;
        bf16x8 raw = *(const bf16x8*)&Xin[row * DIM + k0];
#pragma unroll
        for (int j = 0; j < 8; j++) {
            float v = fmaxf(bf2f(raw[j]) * nd + bias[k0 + j], 0.0f) * ns;
            ((short*)&afrag[kt])[j] = f2bf(v);
        }
    }
#pragma unroll
    for (int nt = 0; nt < 8; nt++) {
        f32x4 acc = {0.f, 0.f, 0.f, 0.f};
        const int c = nt * 16 + lr;
#pragma unroll
        for (int kt = 0; kt < 4; kt++) {
            bf16x8 b = *(const bf16x8*)&Wt[wt_off(c, kt * 32 + q * 8)];
            acc = __builtin_amdgcn_mfma_f32_16x16x32_bf16(afrag[kt], b, acc, 0, 0, 0);
        }
#pragma unroll
        for (int r = 0; r < 4; r++)
            Xout[(row0 + q * 4 + r) * DIM + c] = __float2bfloat16(acc[r]);
    }
}

// ---------------------------------------------------------------------------
// CSR gather, one wave per node, width-16 async global->LDS staging.
// R6 lesson: vmcnt is FIFO -> decouple idx fetch from row staging.
// R7 lesson: occupancy matters as much as MLP (32KB LDS + readlane chains
// -> 35% occ -> 430us). Now: 4 rows per glds instr (64 lanes x 16B), only
// 4 glds per 16-edge batch, idx broadcast via __shfl (register-only), 16KB
// LDS, exec-masked tail (no overfetch).
// FUSE=0: write aggregated row as packed bf16 pairs.
// FUSE=1: fused readout — v = sum_j relu(agg_j*nd+b2_j)*W3_j, one atomic/node.
template <int FUSE>
__global__ __launch_bounds__(256) void gather_kernel(
    const int* __restrict__ row, const int* __restrict__ esrc,
    const unsigned int* __restrict__ Xb, unsigned int* __restrict__ AGGb,
    const float* __restrict__ norm_dst, const float* __restrict__ b2,
    const float* __restrict__ W3, const int* __restrict__ gids,
    float* __restrict__ gsum) {
    __shared__ unsigned int buf[4][GR][64];    // 16 KB
    const int wave = threadIdx.x >> 6;
    const int lane = threadIdx.x & 63;
    const int sub  = lane >> 4;                // row-within-glds (0..3)
    const int col  = lane & 15;                // 16B chunk within row
    const int n = (blockIdx.x * 256 + threadIdx.x) >> 6;   // wave-uniform
    const int s0 = row[n], s1 = row[n + 1];
    float ax = 0.f, ay = 0.f;

    for (int e = s0; e < s1; e += GR) {
        const int cnt = min(GR, s1 - e);       // wave-uniform
        // one coalesced load pulls the batch's indices into lanes 0..cnt-1
        int li = esrc[min(e + lane, s1 - 1)];
        // 4 rows per glds instruction; idx broadcast via shfl (no vmcnt)
#pragma unroll
        for (int b = 0; b < GR / 4; b++) {
            int idx = __shfl(li, b * 4 + sub);
            if (b * 4 + sub < cnt)             // exec-mask unwanted tail rows
                rows4_to_lds(Xb + idx * 64 + col * 4, &buf[wave][b * 4][0]);
        }
        __builtin_amdgcn_s_waitcnt(0x0F70);    // vmcnt(0)
        __builtin_amdgcn_wave_barrier();
#pragma unroll
        for (int r = 0; r < GR; r++) {
            if (r < cnt) {
                unsigned int u = buf[wave][r][lane];
                ax += __uint_as_float(u << 16);
                ay += __uint_as_float(u & 0xffff0000u);
            }
        }
        __builtin_amdgcn_wave_barrier();   // next batch's LDS writes stay below
    }

    if (FUSE == 0) {
        unsigned int lo = (unsigned int)(unsigned short)f2bf(ax);
        unsigned int hi = (unsigned int)(unsigned short)f2bf(ay);
        AGGb[n * 64 + lane] = lo | (hi << 16);
    } else {
        int j = lane * 2;
        float nd = norm_dst[n];
        float v = fmaxf(ax * nd + b2[j], 0.0f) * W3[j]
                + fmaxf(ay * nd + b2[j + 1], 0.0f) * W3[j + 1];
#pragma unroll
        for (int off = 32; off; off >>= 1) v += __shfl_down(v, off);
        if (lane == 0) atomicAdd(&gsum[gids[n]], v);
    }
}

// out[g] = gsum[g] / max(cnt,1) + b3
__global__ __launch_bounds__(256) void final_kernel(
    const float* __restrict__ gsum, const int* __restrict__ gstart,
    const float* __restrict__ b3, float* __restrict__ out) {
    int g = blockIdx.x * 256 + threadIdx.x;
    if (g < NG) {
        float cnt = (float)(gstart[g + 1] - gstart[g]);
        out[g] = gsum[g] / fmaxf(cnt, 1.0f) + b3[0];
    }
}

// ---------------------------------------------------------------------------
extern "C" void kernel_launch(void* const* d_in, const int* in_sizes, int n_in,
                              void* d_out, int out_size, void* d_ws, size_t ws_size,
                              hipStream_t stream) {
    const float* h   = (const float*)d_in[0];
    const int* src   = (const int*)d_in[1];
    const int* dst   = (const int*)d_in[2];
    const int* gids  = (const int*)d_in[3];
    const float* W1  = (const float*)d_in[5];
    const float* b1  = (const float*)d_in[6];
    const float* W2  = (const float*)d_in[7];
    const float* b2  = (const float*)d_in[8];
    const float* W3  = (const float*)d_in[9];
    const float* b3  = (const float*)d_in[10];

    // workspace layout (256B-aligned)
    const size_t OFF_NRM  = 0;                 // 2*NN fp32
    const size_t OFF_CIN  = 800256;            // NN int
    const size_t OFF_COUT = 1200640;           // NN int
    const size_t OFF_ROW  = 1601024;           // NN+1 int
    const size_t OFF_CUR  = 2001664;           // NN int
    const size_t OFF_BSUM = 2402304;           // NB int
    const size_t OFF_GST  = 2404352;           // NG+1 int
    const size_t OFF_GSUM = 2406656;           // NG fp32
    const size_t OFF_ESRC = 2408704;           // NE int
    const size_t OFF_X    = 8808960;           // NN*DIM bf16
    const size_t OFF_AGG  = 34408960;          // NN*DIM bf16
    const size_t REQUIRED = 60008960;          // ~60 MB
    if (ws_size < REQUIRED) {
        hipMemsetAsync(d_out, 0, out_size * sizeof(float), stream);
        return;
    }
    char* ws = (char*)d_ws;
    float* norm_src = (float*)(ws + OFF_NRM);
    float* norm_dst = norm_src + NN;
    int*   cin      = (int*)(ws + OFF_CIN);
    int*   cout_    = (int*)(ws + OFF_COUT);
    int*   row      = (int*)(ws + OFF_ROW);
    int*   cursor   = (int*)(ws + OFF_CUR);
    int*   bsum     = (int*)(ws + OFF_BSUM);
    int*   gstart   = (int*)(ws + OFF_GST);
    float* gsum     = (float*)(ws + OFF_GSUM);
    int*   esrc     = (int*)(ws + OFF_ESRC);
    __hip_bfloat16* X    = (__hip_bfloat16*)(ws + OFF_X);
    unsigned int*   Xb   = (unsigned int*)(ws + OFF_X);
    __hip_bfloat16* AGG  = (__hip_bfloat16*)(ws + OFF_AGG);
    unsigned int*   AGGb = (unsigned int*)(ws + OFF_AGG);

    const int eb = (NE / 4 + 255) / 256;

    // 1. CSR build + norms (+ gsum zero)
    hipMemsetAsync(cin, 0, 800768, stream);    // cin + cout contiguous
    hipMemsetAsync(gsum, 0, 2048, stream);
    hist_kernel<<<eb, 256, 0, stream>>>(src, dst, cin, cout_);
    norm_kernel<<<(NN + 255) / 256, 256, 0, stream>>>(cin, cout_, norm_src, norm_dst);
    scan1_kernel<<<NB, 256, 0, stream>>>(cin, row, bsum);
    scan2_kernel<<<1, 512, 0, stream>>>(bsum);
    scan3_kernel<<<NB, 256, 0, stream>>>(row, bsum, cursor);
    fill_kernel<<<eb, 256, 0, stream>>>(src, dst, cursor, esrc);
    gstart_kernel<<<3, 256, 0, stream>>>(gids, gstart);

    const int gemm_grid = (NN / 16 + 3) / 4;

    // 2. layer 1: project (MFMA, bf16 out), CSR gather (bf16 out)
    gemm1_mfma<<<gemm_grid, 256, 0, stream>>>(h, norm_src, W1, X);
    gather_kernel<0><<<NN / 4, 256, 0, stream>>>(row, esrc, Xb, AGGb,
                                                 norm_dst, b2, W3, gids, gsum);

    // 3. layer 2: fused pre-op + project, then gather fused with readout
    gemm2_mfma<<<gemm_grid, 256, 0, stream>>>(AGG, norm_src, norm_dst, b1, W2, X);
    gather_kernel<1><<<NN / 4, 256, 0, stream>>>(row, esrc, Xb, AGGb,
                                                 norm_dst, b2, W3, gids, gsum);

    // 4. final: per-graph mean + bias
    final_kernel<<<2, 256, 0, stream>>>(gsum, gstart, b3, (float*)d_out);
}